// Round 5
// baseline (99.136 us; speedup 1.0000x reference)
//
#include <hip/hip_runtime.h>
#include <math.h>

constexpr int BATCH = 256;

// ---------------------------------------------------------------------------
// basis_eval: 8 cubic B-spline values + silu for one (b, ii). out[0..7]=basis,
// out[8]=silu(x).
// ---------------------------------------------------------------------------
__device__ __forceinline__ void basis_eval(
    float x, const float* __restrict__ grid, int ii, float out[9])
{
    float g[6];
#pragma unroll
    for (int k = 0; k < 6; ++k) g[k] = grid[(size_t)ii * 6 + k];
    float h = (g[5] - g[0]) * 0.2f;

    float t[12];
    t[0] = g[0] - 3.f * h; t[1] = g[0] - 2.f * h; t[2] = g[0] - h;
#pragma unroll
    for (int k = 0; k < 6; ++k) t[3 + k] = g[k];
    t[9] = g[5] + h; t[10] = g[5] + 2.f * h; t[11] = g[5] + 3.f * h;

    float Bv[11];
#pragma unroll
    for (int j = 0; j < 11; ++j)
        Bv[j] = (x >= t[j] && x < t[j + 1]) ? 1.0f : 0.0f;

#pragma unroll
    for (int d = 1; d <= 3; ++d) {
#pragma unroll
        for (int j = 0; j + d < 11; ++j) {
            float left  = __fdividef(x - t[j],       t[j + d] - t[j]);
            float right = __fdividef(t[j + d + 1] - x, t[j + d + 1] - t[j + 1]);
            Bv[j] = left * Bv[j] + right * Bv[j + 1];
        }
    }

#pragma unroll
    for (int k = 0; k < 8; ++k) out[k] = Bv[k];
    out[8] = __fdividef(x, 1.0f + __expf(-x));
}

// ---------------------------------------------------------------------------
// merge: wcA = 12-float AoS records (ssp*coef[0..7], sb) for xout LDS staging;
//        wcS = 9 SoA planes [p][O*I] for the stats pass.
// ---------------------------------------------------------------------------
__device__ __forceinline__ void merge_body(
    const float* __restrict__ coef, const float* __restrict__ ssp,
    const float* __restrict__ sb, float* __restrict__ wcA,
    float* __restrict__ wcS, size_t OI, int s)
{
    float sspv = ssp[s], sbv = sb[s];
    const float4* c = (const float4*)(coef + (size_t)s * 8);
    float4 c0 = c[0], c1 = c[1];
    float4* w = (float4*)(wcA + (size_t)s * 12);
    float4 m0 = make_float4(sspv * c0.x, sspv * c0.y, sspv * c0.z, sspv * c0.w);
    float4 m1 = make_float4(sspv * c1.x, sspv * c1.y, sspv * c1.z, sspv * c1.w);
    w[0] = m0; w[1] = m1; w[2] = make_float4(sbv, 0.f, 0.f, 0.f);
    wcS[0 * OI + s] = m0.x; wcS[1 * OI + s] = m0.y;
    wcS[2 * OI + s] = m0.z; wcS[3 * OI + s] = m0.w;
    wcS[4 * OI + s] = m1.x; wcS[5 * OI + s] = m1.y;
    wcS[6 * OI + s] = m1.z; wcS[7 * OI + s] = m1.w;
    wcS[8 * OI + s] = sbv;
}

// ---------------------------------------------------------------------------
// xout sweep (unchanged structure): OTA=16 x IR=16 per block, threads = b.
// wcA tile staged in LDS. xpart: [I/16][O][BATCH]
// ---------------------------------------------------------------------------
template <int I, int O>
__device__ __forceinline__ void xout_body(
    const float4* __restrict__ basA4, const float* __restrict__ siluT,
    const float* __restrict__ wcA, float* __restrict__ xpart, int og, int sp)
{
    constexpr int OTA = 16, IR = 16;
    constexpr int NF4 = OTA * IR * 3;   // 768 float4 = 12 KB
    __shared__ float4 wcs[NF4];

    int t = threadIdx.x, lane = t & 63, w = t >> 6;
    int ii0 = sp * IR;

#pragma unroll
    for (int u = 0; u < 3; ++u) {
        int f = t + u * 256;
        int o_r = f / (IR * 3), c = f % (IR * 3);
        wcs[f] = ((const float4*)(wcA + ((size_t)(og * OTA + o_r) * I + ii0) * 12))[c];
    }
    __syncthreads();

    float acc[4][4];
#pragma unroll
    for (int j = 0; j < 4; ++j)
#pragma unroll
        for (int q = 0; q < 4; ++q) acc[j][q] = 0.f;

    for (int i = 0; i < IR; ++i) {
        int ii = ii0 + i;
        float4 a0[4], a1[4]; float sv[4];
#pragma unroll
        for (int j = 0; j < 4; ++j) {
            int b = lane + 64 * j;
            a0[j] = basA4[(size_t)(ii * 2 + 0) * BATCH + b];
            a1[j] = basA4[(size_t)(ii * 2 + 1) * BATCH + b];
            sv[j] = siluT[(size_t)ii * BATCH + b];
        }
#pragma unroll
        for (int q = 0; q < 4; ++q) {
            const float* wr = (const float*)&wcs[((w * 4 + q) * IR + i) * 3];
            float4 c0 = ((const float4*)wr)[0];
            float4 c1 = ((const float4*)wr)[1];
            float c8 = wr[8];
#pragma unroll
            for (int j = 0; j < 4; ++j) {
                acc[j][q] += a0[j].x * c0.x + a0[j].y * c0.y + a0[j].z * c0.z + a0[j].w * c0.w
                           + a1[j].x * c1.x + a1[j].y * c1.y + a1[j].z * c1.z + a1[j].w * c1.w
                           + sv[j] * c8;
            }
        }
    }

#pragma unroll
    for (int q = 0; q < 4; ++q) {
        int oo = og * OTA + w * 4 + q;
#pragma unroll
        for (int j = 0; j < 4; ++j)
            xpart[((size_t)sp * O + oo) * BATCH + lane + 64 * j] = acc[j][q];
    }
}

// ---------------------------------------------------------------------------
// stats sweep (SoA): thread = ii, 8 o's in regs, BCH=32 b's per block.
// All loads lane-stride-4B coalesced. spart: [8][3][O*I]
// ---------------------------------------------------------------------------
template <int I, int O>
__device__ __forceinline__ void stats_body(
    const float* __restrict__ basS, const float* __restrict__ wcS,
    float* __restrict__ spart, int og, int ch, int isp)
{
    constexpr int OTB = 8, BCH = 32;
    const size_t OI = (size_t)O * I, BI = (size_t)BATCH * I;
    int ii = isp * 256 + threadIdx.x;

    float wcr[OTB][9];
#pragma unroll
    for (int o = 0; o < OTB; ++o) {
        size_t s = (size_t)(og * OTB + o) * I + ii;
#pragma unroll
        for (int p = 0; p < 9; ++p) wcr[o][p] = wcS[p * OI + s];
    }

    float aab[OTB], asum[OTB], asq[OTB];
#pragma unroll
    for (int o = 0; o < OTB; ++o) { aab[o] = 0.f; asum[o] = 0.f; asq[o] = 0.f; }

    for (int bl = 0; bl < BCH; ++bl) {
        int b = ch * BCH + bl;
        size_t base = (size_t)b * I + ii;
        float f[9];
#pragma unroll
        for (int p = 0; p < 9; ++p) f[p] = basS[p * BI + base];
#pragma unroll
        for (int o = 0; o < OTB; ++o) {
            float y = wcr[o][8] * f[8];
#pragma unroll
            for (int p = 0; p < 8; ++p) y = fmaf(f[p], wcr[o][p], y);
            aab[o] += fabsf(y);
            asum[o] += y;
            asq[o] = fmaf(y, y, asq[o]);
        }
    }

    size_t cb = (size_t)ch * 3 * OI;
#pragma unroll
    for (int o = 0; o < OTB; ++o) {
        size_t s = (size_t)(og * OTB + o) * I + ii;
        spart[cb + s]          = aab[o];
        spart[cb + OI + s]     = asum[o];
        spart[cb + 2 * OI + s] = asq[o];
    }
}

__device__ __forceinline__ void statsfin_body(
    const float* __restrict__ spart, const float* __restrict__ grid,
    float* __restrict__ sc, float* __restrict__ st, int size, int s)
{
    float ab = 0.f, sm = 0.f, sq = 0.f;
#pragma unroll
    for (int k = 0; k < 8; ++k) {
        size_t base = (size_t)k * 3 * (size_t)size;
        ab += spart[base + s];
        sm += spart[base + (size_t)size + s];
        sq += spart[base + 2 * (size_t)size + s];
    }
    float range = grid[(size_t)s * 6 + 5] - grid[(size_t)s * 6 + 0] + 1e-4f;
    sc[s] = (ab * (1.0f / BATCH)) / range;
    float var = (sq - sm * sm * (1.0f / BATCH)) * (1.0f / (BATCH - 1));
    st[s] = sqrtf(fmaxf(var, 0.0f));
}

// ---------------------------------------------------------------------------
// K1: merge0(512) | merge1(512) | basisN0(256, ii-fast -> SoA planes)
//     | basisT0(256, b-fast -> basA4/siluT)                  -> 1536 blocks
// ---------------------------------------------------------------------------
__global__ __launch_bounds__(256) void k1_prep(
    const float* __restrict__ coef0, const float* __restrict__ ssp0,
    const float* __restrict__ sb0, float* __restrict__ wcA0, float* __restrict__ wcS0,
    const float* __restrict__ coef1, const float* __restrict__ ssp1,
    const float* __restrict__ sb1, float* __restrict__ wcA1, float* __restrict__ wcS1,
    const float* __restrict__ x, const float* __restrict__ grid0,
    float4* __restrict__ basA0, float* __restrict__ siluT0, float* __restrict__ basS0)
{
    int bid = blockIdx.x, t = threadIdx.x;
    if (bid < 512) { merge_body(coef0, ssp0, sb0, wcA0, wcS0, 131072, bid * 256 + t); return; }
    if (bid < 1024) { merge_body(coef1, ssp1, sb1, wcA1, wcS1, 131072, (bid - 512) * 256 + t); return; }
    if (bid < 1280) {
        int tile = bid - 1024;                 // 16 bt x 16 iit
        int ii = (tile % 16) * 16 + (t & 15);  // ii lane-fastest
        int b  = (tile / 16) * 16 + (t >> 4);
        float out[9];
        basis_eval(x[(size_t)b * 256 + ii], grid0, ii, out);
#pragma unroll
        for (int p = 0; p < 9; ++p) basS0[(size_t)p * 65536 + (size_t)b * 256 + ii] = out[p];
        return;
    }
    int tile = bid - 1280;
    int ii = (tile % 16) * 16 + (t >> 4);      // b lane-fastest
    int b  = (tile / 16) * 16 + (t & 15);
    float out[9];
    basis_eval(x[(size_t)b * 256 + ii], grid0, ii, out);
    basA0[(size_t)(ii * 2 + 0) * BATCH + b] = make_float4(out[0], out[1], out[2], out[3]);
    basA0[(size_t)(ii * 2 + 1) * BATCH + b] = make_float4(out[4], out[5], out[6], out[7]);
    siluT0[(size_t)ii * BATCH + b] = out[8];
}

// ---------------------------------------------------------------------------
// K2: xout0 only (og32 x sp16 = 512 blocks) — shortest critical-path link.
// ---------------------------------------------------------------------------
__global__ __launch_bounds__(256) void k2_xout0(
    const float4* __restrict__ basA0, const float* __restrict__ siluT0,
    const float* __restrict__ wcA0, float* __restrict__ xpart0)
{
    xout_body<256, 512>(basA0, siluT0, wcA0, xpart0, blockIdx.x / 16, blockIdx.x % 16);
}

// ---------------------------------------------------------------------------
// K3: basisT1(512) | basisN1(512, LDS-transposed xmid) | stats0(512)
//                                                          -> 1536 blocks
// xmid = bias0 + sum_k xpart0[k]  (never materialized)
// ---------------------------------------------------------------------------
__global__ __launch_bounds__(256) void k3_basis1_stats0(
    const float* __restrict__ xpart0, const float* __restrict__ bias0,
    const float* __restrict__ grid1,
    float4* __restrict__ basA1, float* __restrict__ siluT1, float* __restrict__ basS1,
    const float* __restrict__ basS0, const float* __restrict__ wcS0,
    float* __restrict__ spart0)
{
    __shared__ float ldsX[16][17];
    int bid = blockIdx.x, t = threadIdx.x;
    if (bid < 512) {
        // basisT1: b lane-fastest. tiles: bt in [0,16), iit in [0,32)
        int tile = bid;
        int ii = (tile % 32) * 16 + (t >> 4);
        int b  = (tile / 32) * 16 + (t & 15);
        float xv = bias0[ii];
#pragma unroll
        for (int k = 0; k < 16; ++k)
            xv += xpart0[(size_t)k * 131072 + (size_t)ii * 256 + b];
        float out[9];
        basis_eval(xv, grid1, ii, out);
        basA1[(size_t)(ii * 2 + 0) * BATCH + b] = make_float4(out[0], out[1], out[2], out[3]);
        basA1[(size_t)(ii * 2 + 1) * BATCH + b] = make_float4(out[4], out[5], out[6], out[7]);
        siluT1[(size_t)ii * BATCH + b] = out[8];
        return;
    }
    if (bid < 1024) {
        // basisN1: compute xmid b-fast (coalesced), transpose via LDS, then ii-fast.
        int tile = bid - 512;
        int iiA = (tile % 32) * 16 + (t >> 4);
        int bA  = (tile / 32) * 16 + (t & 15);
        float xv = bias0[iiA];
#pragma unroll
        for (int k = 0; k < 16; ++k)
            xv += xpart0[(size_t)k * 131072 + (size_t)iiA * 256 + bA];
        ldsX[t >> 4][t & 15] = xv;   // [ii_local][b_local]
        __syncthreads();
        int ii = (tile % 32) * 16 + (t & 15);  // ii lane-fastest
        int b  = (tile / 32) * 16 + (t >> 4);
        float out[9];
        basis_eval(ldsX[t & 15][t >> 4], grid1, ii, out);
#pragma unroll
        for (int p = 0; p < 9; ++p) basS1[(size_t)p * 131072 + (size_t)b * 512 + ii] = out[p];
        return;
    }
    int r = bid - 1024;                       // stats0: og in [0,64), ch in [0,8)
    stats_body<256, 512>(basS0, wcS0, spart0, r / 8, r % 8, 0);
}

// ---------------------------------------------------------------------------
// K4: xout1(512) | stats1(512) | statsfin0(512)             -> 1536 blocks
// ---------------------------------------------------------------------------
__global__ __launch_bounds__(256) void k4_sweep1(
    const float4* __restrict__ basA1, const float* __restrict__ siluT1,
    const float* __restrict__ wcA1, float* __restrict__ xpart1,
    const float* __restrict__ basS1, const float* __restrict__ wcS1,
    float* __restrict__ spart1,
    const float* __restrict__ spart0, const float* __restrict__ grid0,
    float* __restrict__ sc0, float* __restrict__ st0)
{
    int bid = blockIdx.x;
    if (bid < 512) {
        xout_body<512, 256>(basA1, siluT1, wcA1, xpart1, bid / 32, bid % 32);
    } else if (bid < 1024) {
        int r = bid - 512;                    // og in [0,32), ch in [0,8), isp in {0,1}
        int og = r / 16, rem = r % 16;
        stats_body<512, 256>(basS1, wcS1, spart1, og, rem % 8, rem / 8);
    } else {
        statsfin_body(spart0, grid0, sc0, st0, 131072,
                      (bid - 1024) * 256 + threadIdx.x);
    }
}

// ---------------------------------------------------------------------------
// K5: xoutfin1(256) | statsfin1(512)                        -> 768 blocks
// ---------------------------------------------------------------------------
__global__ __launch_bounds__(256) void k5_fin(
    const float* __restrict__ xpart1, const float* __restrict__ bias1,
    float* __restrict__ x2,
    const float* __restrict__ spart1, const float* __restrict__ grid1,
    float* __restrict__ sc1, float* __restrict__ st1)
{
    int bid = blockIdx.x, t = threadIdx.x;
    if (bid < 256) {
        int oo = bid, b = t;
        float v = bias1[oo];
#pragma unroll
        for (int k = 0; k < 32; ++k)
            v += xpart1[(size_t)k * 65536 + (size_t)oo * 256 + b];
        x2[(size_t)b * 256 + oo] = v;
    } else {
        statsfin_body(spart1, grid1, sc1, st1, 131072,
                      (bid - 256) * 256 + t);
    }
}

// ---------------------------------------------------------------------------
extern "C" void kernel_launch(void* const* d_in, const int* in_sizes, int n_in,
                              void* d_out, int out_size, void* d_ws, size_t ws_size,
                              hipStream_t stream)
{
    const float* x     = (const float*)d_in[0];
    const float* grid0 = (const float*)d_in[1];
    const float* coef0 = (const float*)d_in[2];
    const float* sb0   = (const float*)d_in[3];
    const float* ssp0  = (const float*)d_in[4];
    const float* bias0 = (const float*)d_in[5];
    const float* grid1 = (const float*)d_in[6];
    const float* coef1 = (const float*)d_in[7];
    const float* sb1   = (const float*)d_in[8];
    const float* ssp1  = (const float*)d_in[9];
    const float* bias1 = (const float*)d_in[10];

    float* out = (float*)d_out;
    float* x2  = out;                 // (256,256)
    float* sc0 = out + 65536;         // (512,256)
    float* st0 = out + 196608;        // (512,256)
    float* sc1 = out + 327680;        // (256,512)
    float* st1 = out + 458752;        // (256,512)

    // Workspace (~78 MB, all disjoint):
    float* w = (float*)d_ws;
    float* basA0  = w; w += 256 * 256 * 8;       // float4 x2 per (ii,b)
    float* siluT0 = w; w += 256 * 256;
    float* basS0  = w; w += 9 * 256 * 256;       // 9 SoA planes [p][b][256]
    float* basA1  = w; w += 512 * 256 * 8;
    float* siluT1 = w; w += 512 * 256;
    float* basS1  = w; w += 9 * 256 * 512;       // [p][b][512]
    float* wcA0   = w; w += 12 * 512 * 256;
    float* wcS0   = w; w += 9 * 512 * 256;
    float* wcA1   = w; w += 12 * 512 * 256;
    float* wcS1   = w; w += 9 * 512 * 256;
    float* xpart0 = w; w += 16 * 512 * 256;      // [16][512][256]
    float* xpart1 = w; w += 32 * 256 * 256;      // [32][256][256]
    float* spart0 = w; w += 8 * 3 * 512 * 256;   // [8][3][131072]
    float* spart1 = w; w += 8 * 3 * 256 * 512;   // [8][3][131072]

    k1_prep<<<1536, 256, 0, stream>>>(
        coef0, ssp0, sb0, wcA0, wcS0,
        coef1, ssp1, sb1, wcA1, wcS1,
        x, grid0, (float4*)basA0, siluT0, basS0);

    k2_xout0<<<512, 256, 0, stream>>>(
        (const float4*)basA0, siluT0, wcA0, xpart0);

    k3_basis1_stats0<<<1536, 256, 0, stream>>>(
        xpart0, bias0, grid1, (float4*)basA1, siluT1, basS1,
        basS0, wcS0, spart0);

    k4_sweep1<<<1536, 256, 0, stream>>>(
        (const float4*)basA1, siluT1, wcA1, xpart1,
        basS1, wcS1, spart1,
        spart0, grid0, sc0, st0);

    k5_fin<<<768, 256, 0, stream>>>(
        xpart1, bias1, x2, spart1, grid1, sc1, st1);
}

// Round 6
// 85.806 us; speedup vs baseline: 1.1553x; 1.1553x over previous
//
#include <hip/hip_runtime.h>
#include <math.h>

constexpr int BATCH = 256;

// ---------------------------------------------------------------------------
// basis_eval: 8 cubic B-spline values + silu. out[0..7]=basis, out[8]=silu.
// ---------------------------------------------------------------------------
__device__ __forceinline__ void basis_eval(
    float x, const float* __restrict__ grid, int ii, float out[9])
{
    float g[6];
#pragma unroll
    for (int k = 0; k < 6; ++k) g[k] = grid[(size_t)ii * 6 + k];
    float h = (g[5] - g[0]) * 0.2f;

    float t[12];
    t[0] = g[0] - 3.f * h; t[1] = g[0] - 2.f * h; t[2] = g[0] - h;
#pragma unroll
    for (int k = 0; k < 6; ++k) t[3 + k] = g[k];
    t[9] = g[5] + h; t[10] = g[5] + 2.f * h; t[11] = g[5] + 3.f * h;

    float Bv[11];
#pragma unroll
    for (int j = 0; j < 11; ++j)
        Bv[j] = (x >= t[j] && x < t[j + 1]) ? 1.0f : 0.0f;

#pragma unroll
    for (int d = 1; d <= 3; ++d) {
#pragma unroll
        for (int j = 0; j + d < 11; ++j) {
            float left  = __fdividef(x - t[j],         t[j + d] - t[j]);
            float right = __fdividef(t[j + d + 1] - x, t[j + d + 1] - t[j + 1]);
            Bv[j] = left * Bv[j] + right * Bv[j + 1];
        }
    }

#pragma unroll
    for (int k = 0; k < 8; ++k) out[k] = Bv[k];
    out[8] = __fdividef(x, 1.0f + __expf(-x));
}

// ---------------------------------------------------------------------------
// merge: wcA[s*12+k] = ssp[s]*coef[s*8+k] (k<8), wcA[s*12+8] = sb[s]
// ---------------------------------------------------------------------------
__device__ __forceinline__ void merge_body(
    const float* __restrict__ coef, const float* __restrict__ ssp,
    const float* __restrict__ sb, float* __restrict__ wcA, int s)
{
    float sspv = ssp[s], sbv = sb[s];
    const float4* c = (const float4*)(coef + (size_t)s * 8);
    float4 c0 = c[0], c1 = c[1];
    float4* w = (float4*)(wcA + (size_t)s * 12);
    w[0] = make_float4(sspv * c0.x, sspv * c0.y, sspv * c0.z, sspv * c0.w);
    w[1] = make_float4(sspv * c1.x, sspv * c1.y, sspv * c1.z, sspv * c1.w);
    w[2] = make_float4(sbv, 0.f, 0.f, 0.f);
}

// ---------------------------------------------------------------------------
// xout sweep: OTA=16 x IR=16 per block; threads = b (4/thread).
// wcA tile staged in LDS. xpart: [I/16][O][BATCH]
// ---------------------------------------------------------------------------
template <int I, int O>
__device__ __forceinline__ void xout_body(
    const float4* __restrict__ basA4, const float* __restrict__ siluT,
    const float* __restrict__ wcA, float* __restrict__ xpart, int og, int sp)
{
    constexpr int OTA = 16, IR = 16;
    constexpr int NF4 = OTA * IR * 3;   // 768 float4 = 12 KB
    __shared__ float4 wcs[NF4];

    int t = threadIdx.x, lane = t & 63, w = t >> 6;
    int ii0 = sp * IR;

#pragma unroll
    for (int u = 0; u < 3; ++u) {
        int f = t + u * 256;
        int o_r = f / (IR * 3), c = f % (IR * 3);
        wcs[f] = ((const float4*)(wcA + ((size_t)(og * OTA + o_r) * I + ii0) * 12))[c];
    }
    __syncthreads();

    float acc[4][4];
#pragma unroll
    for (int j = 0; j < 4; ++j)
#pragma unroll
        for (int q = 0; q < 4; ++q) acc[j][q] = 0.f;

    for (int i = 0; i < IR; ++i) {
        int ii = ii0 + i;
        float4 a0[4], a1[4]; float sv[4];
#pragma unroll
        for (int j = 0; j < 4; ++j) {
            int b = lane + 64 * j;
            a0[j] = basA4[(size_t)(ii * 2 + 0) * BATCH + b];
            a1[j] = basA4[(size_t)(ii * 2 + 1) * BATCH + b];
            sv[j] = siluT[(size_t)ii * BATCH + b];
        }
#pragma unroll
        for (int q = 0; q < 4; ++q) {
            const float* wr = (const float*)&wcs[((w * 4 + q) * IR + i) * 3];
            float4 c0 = ((const float4*)wr)[0];
            float4 c1 = ((const float4*)wr)[1];
            float c8 = wr[8];
#pragma unroll
            for (int j = 0; j < 4; ++j) {
                acc[j][q] += a0[j].x * c0.x + a0[j].y * c0.y + a0[j].z * c0.z + a0[j].w * c0.w
                           + a1[j].x * c1.x + a1[j].y * c1.y + a1[j].z * c1.z + a1[j].w * c1.w
                           + sv[j] * c8;
            }
        }
    }

#pragma unroll
    for (int q = 0; q < 4; ++q) {
        int oo = og * OTA + w * 4 + q;
#pragma unroll
        for (int j = 0; j < 4; ++j)
            xpart[((size_t)sp * O + oo) * BATCH + lane + 64 * j] = acc[j][q];
    }
}

// ---------------------------------------------------------------------------
// stats sweep: thread = ii (ii = isp*256+t), 8 o's, BCH=64 b's per block.
// Reads merged wcA (9 FMA/y). spart: [4][3][O*I]
// ---------------------------------------------------------------------------
template <int I, int O>
__device__ __forceinline__ void stats_body(
    const float* __restrict__ basB, const float* __restrict__ siluN,
    const float* __restrict__ wcA, float* __restrict__ spart,
    int og, int ch, int isp)
{
    constexpr int OTB = 8, BCH = 64;
    const size_t OI = (size_t)O * I;
    int ii = isp * 256 + threadIdx.x;

    float wcr[OTB][9];
#pragma unroll
    for (int o = 0; o < OTB; ++o) {
        size_t s = (size_t)(og * OTB + o) * I + ii;
        const float4* p = (const float4*)(wcA + s * 12);
        float4 c0 = p[0], c1 = p[1];
        wcr[o][0] = c0.x; wcr[o][1] = c0.y; wcr[o][2] = c0.z; wcr[o][3] = c0.w;
        wcr[o][4] = c1.x; wcr[o][5] = c1.y; wcr[o][6] = c1.z; wcr[o][7] = c1.w;
        wcr[o][8] = wcA[s * 12 + 8];
    }

    float aab[OTB], asum[OTB], asq[OTB];
#pragma unroll
    for (int o = 0; o < OTB; ++o) { aab[o] = 0.f; asum[o] = 0.f; asq[o] = 0.f; }

    for (int bl = 0; bl < BCH; ++bl) {
        int b = ch * BCH + bl;
        const float4* ba = (const float4*)(basB + ((size_t)b * I + ii) * 8);
        float4 a0 = ba[0], a1 = ba[1];
        float sv = siluN[(size_t)b * I + ii];
#pragma unroll
        for (int o = 0; o < OTB; ++o) {
            float y = wcr[o][8] * sv;
            y = fmaf(a0.x, wcr[o][0], y); y = fmaf(a0.y, wcr[o][1], y);
            y = fmaf(a0.z, wcr[o][2], y); y = fmaf(a0.w, wcr[o][3], y);
            y = fmaf(a1.x, wcr[o][4], y); y = fmaf(a1.y, wcr[o][5], y);
            y = fmaf(a1.z, wcr[o][6], y); y = fmaf(a1.w, wcr[o][7], y);
            aab[o] += fabsf(y);
            asum[o] += y;
            asq[o] = fmaf(y, y, asq[o]);
        }
    }

    size_t cb = (size_t)ch * 3 * OI;
#pragma unroll
    for (int o = 0; o < OTB; ++o) {
        size_t s = (size_t)(og * OTB + o) * I + ii;
        spart[cb + s]          = aab[o];
        spart[cb + OI + s]     = asum[o];
        spart[cb + 2 * OI + s] = asq[o];
    }
}

__device__ __forceinline__ void statsfin_body(
    const float* __restrict__ spart, const float* __restrict__ grid,
    float* __restrict__ sc, float* __restrict__ st, int size, int s)
{
    float ab = 0.f, sm = 0.f, sq = 0.f;
#pragma unroll
    for (int k = 0; k < 4; ++k) {
        size_t base = (size_t)k * 3 * (size_t)size;
        ab += spart[base + s];
        sm += spart[base + (size_t)size + s];
        sq += spart[base + 2 * (size_t)size + s];
    }
    float range = grid[(size_t)s * 6 + 5] - grid[(size_t)s * 6 + 0] + 1e-4f;
    sc[s] = (ab * (1.0f / BATCH)) / range;
    float var = (sq - sm * sm * (1.0f / BATCH)) * (1.0f / (BATCH - 1));
    st[s] = sqrtf(fmaxf(var, 0.0f));
}

// ---------------------------------------------------------------------------
// K1: merge0(512) | merge1(512) | basis0-dual(256 tiles, LDS transpose)
// ---------------------------------------------------------------------------
__global__ __launch_bounds__(256) void k1_prep(
    const float* __restrict__ coef0, const float* __restrict__ ssp0,
    const float* __restrict__ sb0, float* __restrict__ wcA0,
    const float* __restrict__ coef1, const float* __restrict__ ssp1,
    const float* __restrict__ sb1, float* __restrict__ wcA1,
    const float* __restrict__ x, const float* __restrict__ grid0,
    float4* __restrict__ basA0, float* __restrict__ siluT0,
    float* __restrict__ basB0, float* __restrict__ siluN0)
{
    __shared__ float lds[9][16][17];
    int bid = blockIdx.x, t = threadIdx.x;
    if (bid < 512)  { merge_body(coef0, ssp0, sb0, wcA0, bid * 256 + t); return; }
    if (bid < 1024) { merge_body(coef1, ssp1, sb1, wcA1, (bid - 512) * 256 + t); return; }
    int tile = bid - 1024;                 // 16 bt x 16 it
    int bt = tile / 16, it = tile % 16;
    // phase 1: ii lane-fastest -> dense basB/siluN writes
    {
        int ii = it * 16 + (t & 15), b = bt * 16 + (t >> 4);
        float out[9];
        basis_eval(x[(size_t)b * 256 + ii], grid0, ii, out);
        float4* pB = (float4*)(basB0 + ((size_t)b * 256 + ii) * 8);
        pB[0] = make_float4(out[0], out[1], out[2], out[3]);
        pB[1] = make_float4(out[4], out[5], out[6], out[7]);
        siluN0[(size_t)b * 256 + ii] = out[8];
#pragma unroll
        for (int p = 0; p < 9; ++p) lds[p][t & 15][t >> 4] = out[p];
    }
    __syncthreads();
    // phase 2: b lane-fastest -> dense basA/siluT writes
    {
        int ii = it * 16 + (t >> 4), b = bt * 16 + (t & 15);
        float o[9];
#pragma unroll
        for (int p = 0; p < 9; ++p) o[p] = lds[p][t >> 4][t & 15];
        basA0[(size_t)(ii * 2 + 0) * BATCH + b] = make_float4(o[0], o[1], o[2], o[3]);
        basA0[(size_t)(ii * 2 + 1) * BATCH + b] = make_float4(o[4], o[5], o[6], o[7]);
        siluT0[(size_t)ii * BATCH + b] = o[8];
    }
}

// ---------------------------------------------------------------------------
// K2: xout0 (512: og32 x sp16) | stats0 (256: og64 x ch4)     -> 768 blocks
// ---------------------------------------------------------------------------
__global__ __launch_bounds__(256) void k2_sweep0(
    const float4* __restrict__ basA0, const float* __restrict__ siluT0,
    const float* __restrict__ wcA0, float* __restrict__ xpart0,
    const float* __restrict__ basB0, const float* __restrict__ siluN0,
    float* __restrict__ spart0)
{
    int bid = blockIdx.x;
    if (bid < 512) {
        xout_body<256, 512>(basA0, siluT0, wcA0, xpart0, bid / 16, bid % 16);
    } else {
        int r = bid - 512;   // og in [0,64), ch in [0,4)
        stats_body<256, 512>(basB0, siluN0, wcA0, spart0, r / 4, r % 4, 0);
    }
}

// ---------------------------------------------------------------------------
// K3: basis1-dual (512 tiles, fused xmid, LDS transpose) | statsfin0 (512)
// ---------------------------------------------------------------------------
__global__ __launch_bounds__(256) void k3_basis1(
    const float* __restrict__ xpart0, const float* __restrict__ bias0,
    const float* __restrict__ grid1,
    float4* __restrict__ basA1, float* __restrict__ siluT1,
    float* __restrict__ basB1, float* __restrict__ siluN1,
    const float* __restrict__ spart0, const float* __restrict__ grid0,
    float* __restrict__ sc0, float* __restrict__ st0)
{
    __shared__ float lds[9][16][17];
    int bid = blockIdx.x, t = threadIdx.x;
    if (bid < 512) {
        int bt = bid / 32, it = bid % 32;       // b tiles 16, ii tiles 32 (I=512)
        // phase 1: b lane-fastest -> coalesced xpart reads, dense basA writes
        {
            int ii = it * 16 + (t >> 4), b = bt * 16 + (t & 15);
            float xv = bias0[ii];
#pragma unroll
            for (int k = 0; k < 16; ++k)
                xv += xpart0[(size_t)k * 131072 + (size_t)ii * 256 + b];
            float out[9];
            basis_eval(xv, grid1, ii, out);
            basA1[(size_t)(ii * 2 + 0) * BATCH + b] = make_float4(out[0], out[1], out[2], out[3]);
            basA1[(size_t)(ii * 2 + 1) * BATCH + b] = make_float4(out[4], out[5], out[6], out[7]);
            siluT1[(size_t)ii * BATCH + b] = out[8];
#pragma unroll
            for (int p = 0; p < 9; ++p) lds[p][t >> 4][t & 15] = out[p];
        }
        __syncthreads();
        // phase 2: ii lane-fastest -> dense basB/siluN writes
        {
            int ii = it * 16 + (t & 15), b = bt * 16 + (t >> 4);
            float o[9];
#pragma unroll
            for (int p = 0; p < 9; ++p) o[p] = lds[p][t & 15][t >> 4];
            float4* pB = (float4*)(basB1 + ((size_t)b * 512 + ii) * 8);
            pB[0] = make_float4(o[0], o[1], o[2], o[3]);
            pB[1] = make_float4(o[4], o[5], o[6], o[7]);
            siluN1[(size_t)b * 512 + ii] = o[8];
        }
        return;
    }
    statsfin_body(spart0, grid0, sc0, st0, 131072, (bid - 512) * 256 + t);
}

// ---------------------------------------------------------------------------
// K4: xout1 (512: og16 x sp32) | stats1 (256: og32 x ch4 x isp2) -> 768 blocks
// ---------------------------------------------------------------------------
__global__ __launch_bounds__(256) void k4_sweep1(
    const float4* __restrict__ basA1, const float* __restrict__ siluT1,
    const float* __restrict__ wcA1, float* __restrict__ xpart1,
    const float* __restrict__ basB1, const float* __restrict__ siluN1,
    float* __restrict__ spart1)
{
    int bid = blockIdx.x;
    if (bid < 512) {
        xout_body<512, 256>(basA1, siluT1, wcA1, xpart1, bid / 32, bid % 32);
    } else {
        int r = bid - 512;   // og in [0,32), rem: ch in [0,4), isp in {0,1}
        int og = r / 8, rem = r % 8;
        stats_body<512, 256>(basB1, siluN1, wcA1, spart1, og, rem % 4, rem / 4);
    }
}

// ---------------------------------------------------------------------------
// K5: xoutfin1 (256) | statsfin1 (512)                       -> 768 blocks
// ---------------------------------------------------------------------------
__global__ __launch_bounds__(256) void k5_fin(
    const float* __restrict__ xpart1, const float* __restrict__ bias1,
    float* __restrict__ x2,
    const float* __restrict__ spart1, const float* __restrict__ grid1,
    float* __restrict__ sc1, float* __restrict__ st1)
{
    int bid = blockIdx.x, t = threadIdx.x;
    if (bid < 256) {
        int oo = bid, b = t;
        float v = bias1[oo];
#pragma unroll
        for (int k = 0; k < 32; ++k)
            v += xpart1[(size_t)k * 65536 + (size_t)oo * 256 + b];
        x2[(size_t)b * 256 + oo] = v;
    } else {
        statsfin_body(spart1, grid1, sc1, st1, 131072, (bid - 256) * 256 + t);
    }
}

// ---------------------------------------------------------------------------
extern "C" void kernel_launch(void* const* d_in, const int* in_sizes, int n_in,
                              void* d_out, int out_size, void* d_ws, size_t ws_size,
                              hipStream_t stream)
{
    const float* x     = (const float*)d_in[0];
    const float* grid0 = (const float*)d_in[1];
    const float* coef0 = (const float*)d_in[2];
    const float* sb0   = (const float*)d_in[3];
    const float* ssp0  = (const float*)d_in[4];
    const float* bias0 = (const float*)d_in[5];
    const float* grid1 = (const float*)d_in[6];
    const float* coef1 = (const float*)d_in[7];
    const float* sb1   = (const float*)d_in[8];
    const float* ssp1  = (const float*)d_in[9];
    const float* bias1 = (const float*)d_in[10];

    float* out = (float*)d_out;
    float* x2  = out;                 // (256,256)
    float* sc0 = out + 65536;         // (512,256)
    float* st0 = out + 196608;        // (512,256)
    float* sc1 = out + 327680;        // (256,512)
    float* st1 = out + 458752;        // (256,512)

    // Workspace (~56 MB, all disjoint):
    float* w = (float*)d_ws;
    float* basA0  = w; w += 256 * 256 * 8;
    float* siluT0 = w; w += 256 * 256;
    float* basB0  = w; w += 256 * 256 * 8;
    float* siluN0 = w; w += 256 * 256;
    float* basA1  = w; w += 512 * 256 * 8;
    float* siluT1 = w; w += 512 * 256;
    float* basB1  = w; w += 512 * 256 * 8;
    float* siluN1 = w; w += 512 * 256;
    float* wcA0   = w; w += 12 * 512 * 256;
    float* wcA1   = w; w += 12 * 512 * 256;
    float* xpart0 = w; w += 16 * 512 * 256;     // [16][512][256]
    float* xpart1 = w; w += 32 * 256 * 256;     // [32][256][256]
    float* spart0 = w; w += 4 * 3 * 512 * 256;  // [4][3][131072]
    float* spart1 = w; w += 4 * 3 * 256 * 512;  // [4][3][131072]

    k1_prep<<<1280, 256, 0, stream>>>(
        coef0, ssp0, sb0, wcA0, coef1, ssp1, sb1, wcA1,
        x, grid0, (float4*)basA0, siluT0, basB0, siluN0);

    k2_sweep0<<<768, 256, 0, stream>>>(
        (const float4*)basA0, siluT0, wcA0, xpart0, basB0, siluN0, spart0);

    k3_basis1<<<1024, 256, 0, stream>>>(
        xpart0, bias0, grid1, (float4*)basA1, siluT1, basB1, siluN1,
        spart0, grid0, sc0, st0);

    k4_sweep1<<<768, 256, 0, stream>>>(
        (const float4*)basA1, siluT1, wcA1, xpart1, basB1, siluN1, spart1);

    k5_fin<<<768, 256, 0, stream>>>(
        xpart1, bias1, x2, spart1, grid1, sc1, st1);
}

// Round 7
// 82.180 us; speedup vs baseline: 1.2063x; 1.0441x over previous
//
#include <hip/hip_runtime.h>
#include <math.h>

constexpr int BATCH = 256;

// ---------------------------------------------------------------------------
// basis_eval: 8 cubic B-spline values + silu. out[0..7]=basis, out[8]=silu.
// ---------------------------------------------------------------------------
__device__ __forceinline__ void basis_eval(
    float x, const float* __restrict__ grid, int ii, float out[9])
{
    float g[6];
#pragma unroll
    for (int k = 0; k < 6; ++k) g[k] = grid[(size_t)ii * 6 + k];
    float h = (g[5] - g[0]) * 0.2f;

    float t[12];
    t[0] = g[0] - 3.f * h; t[1] = g[0] - 2.f * h; t[2] = g[0] - h;
#pragma unroll
    for (int k = 0; k < 6; ++k) t[3 + k] = g[k];
    t[9] = g[5] + h; t[10] = g[5] + 2.f * h; t[11] = g[5] + 3.f * h;

    float Bv[11];
#pragma unroll
    for (int j = 0; j < 11; ++j)
        Bv[j] = (x >= t[j] && x < t[j + 1]) ? 1.0f : 0.0f;

#pragma unroll
    for (int d = 1; d <= 3; ++d) {
#pragma unroll
        for (int j = 0; j + d < 11; ++j) {
            float left  = __fdividef(x - t[j],         t[j + d] - t[j]);
            float right = __fdividef(t[j + d + 1] - x, t[j + d + 1] - t[j + 1]);
            Bv[j] = left * Bv[j] + right * Bv[j + 1];
        }
    }

#pragma unroll
    for (int k = 0; k < 8; ++k) out[k] = Bv[k];
    out[8] = __fdividef(x, 1.0f + __expf(-x));
}

// ---------------------------------------------------------------------------
// merge: wcA[s*12+k] = ssp[s]*coef[s*8+k] (k<8), wcA[s*12+8] = sb[s]
// ---------------------------------------------------------------------------
__device__ __forceinline__ void merge_body(
    const float* __restrict__ coef, const float* __restrict__ ssp,
    const float* __restrict__ sb, float* __restrict__ wcA, int s)
{
    float sspv = ssp[s], sbv = sb[s];
    const float4* c = (const float4*)(coef + (size_t)s * 8);
    float4 c0 = c[0], c1 = c[1];
    float4* w = (float4*)(wcA + (size_t)s * 12);
    w[0] = make_float4(sspv * c0.x, sspv * c0.y, sspv * c0.z, sspv * c0.w);
    w[1] = make_float4(sspv * c1.x, sspv * c1.y, sspv * c1.z, sspv * c1.w);
    w[2] = make_float4(sbv, 0.f, 0.f, 0.f);
}

// ---------------------------------------------------------------------------
// xout sweep v2: OTA=16 o's x IR=16 ii's per block; thread = one b (256 b's).
// Each wave owns a disjoint 64-b slice -> basis tile read ONCE per block.
// Per i: one 36B basis read reused for all 16 o's; wc via LDS broadcast.
// xpart: [I/16][O][BATCH]
// ---------------------------------------------------------------------------
template <int I, int O>
__device__ __forceinline__ void xout_body(
    const float4* __restrict__ basA4, const float* __restrict__ siluT,
    const float* __restrict__ wcA, float* __restrict__ xpart, int og, int sp)
{
    constexpr int OTA = 16, IR = 16;
    constexpr int NF4 = OTA * IR * 3;   // 768 float4 = 12 KB
    __shared__ float4 wcs[NF4];

    int t = threadIdx.x;
    int b = t;                          // thread owns one b
    int ii0 = sp * IR;

#pragma unroll
    for (int u = 0; u < 3; ++u) {
        int f = t + u * 256;
        int o_r = f / (IR * 3), c = f % (IR * 3);
        wcs[f] = ((const float4*)(wcA + ((size_t)(og * OTA + o_r) * I + ii0) * 12))[c];
    }
    __syncthreads();

    float acc[OTA];
#pragma unroll
    for (int o = 0; o < OTA; ++o) acc[o] = 0.f;

    for (int i = 0; i < IR; ++i) {
        int ii = ii0 + i;
        float4 a0 = basA4[(size_t)(ii * 2 + 0) * BATCH + b];
        float4 a1 = basA4[(size_t)(ii * 2 + 1) * BATCH + b];
        float sv = siluT[(size_t)ii * BATCH + b];
#pragma unroll
        for (int o = 0; o < OTA; ++o) {
            const float* wr = (const float*)&wcs[(o * IR + i) * 3];
            float4 c0 = ((const float4*)wr)[0];
            float4 c1 = ((const float4*)wr)[1];
            float c8 = wr[8];
            float y = sv * c8;
            y = fmaf(a0.x, c0.x, y); y = fmaf(a0.y, c0.y, y);
            y = fmaf(a0.z, c0.z, y); y = fmaf(a0.w, c0.w, y);
            y = fmaf(a1.x, c1.x, y); y = fmaf(a1.y, c1.y, y);
            y = fmaf(a1.z, c1.z, y); y = fmaf(a1.w, c1.w, y);
            acc[o] += y;
        }
    }

#pragma unroll
    for (int o = 0; o < OTA; ++o) {
        int oo = og * OTA + o;
        xpart[((size_t)sp * O + oo) * BATCH + b] = acc[o];
    }
}

// ---------------------------------------------------------------------------
// stats sweep: thread = ii (ii = isp*256+t), 8 o's, BCH=64 b's per block.
// Reads merged wcA (9 FMA/y). spart: [4][3][O*I]
// ---------------------------------------------------------------------------
template <int I, int O>
__device__ __forceinline__ void stats_body(
    const float* __restrict__ basB, const float* __restrict__ siluN,
    const float* __restrict__ wcA, float* __restrict__ spart,
    int og, int ch, int isp)
{
    constexpr int OTB = 8, BCH = 64;
    const size_t OI = (size_t)O * I;
    int ii = isp * 256 + threadIdx.x;

    float wcr[OTB][9];
#pragma unroll
    for (int o = 0; o < OTB; ++o) {
        size_t s = (size_t)(og * OTB + o) * I + ii;
        const float4* p = (const float4*)(wcA + s * 12);
        float4 c0 = p[0], c1 = p[1];
        wcr[o][0] = c0.x; wcr[o][1] = c0.y; wcr[o][2] = c0.z; wcr[o][3] = c0.w;
        wcr[o][4] = c1.x; wcr[o][5] = c1.y; wcr[o][6] = c1.z; wcr[o][7] = c1.w;
        wcr[o][8] = wcA[s * 12 + 8];
    }

    float aab[OTB], asum[OTB], asq[OTB];
#pragma unroll
    for (int o = 0; o < OTB; ++o) { aab[o] = 0.f; asum[o] = 0.f; asq[o] = 0.f; }

    for (int bl = 0; bl < BCH; ++bl) {
        int b = ch * BCH + bl;
        const float4* ba = (const float4*)(basB + ((size_t)b * I + ii) * 8);
        float4 a0 = ba[0], a1 = ba[1];
        float sv = siluN[(size_t)b * I + ii];
#pragma unroll
        for (int o = 0; o < OTB; ++o) {
            float y = wcr[o][8] * sv;
            y = fmaf(a0.x, wcr[o][0], y); y = fmaf(a0.y, wcr[o][1], y);
            y = fmaf(a0.z, wcr[o][2], y); y = fmaf(a0.w, wcr[o][3], y);
            y = fmaf(a1.x, wcr[o][4], y); y = fmaf(a1.y, wcr[o][5], y);
            y = fmaf(a1.z, wcr[o][6], y); y = fmaf(a1.w, wcr[o][7], y);
            aab[o] += fabsf(y);
            asum[o] += y;
            asq[o] = fmaf(y, y, asq[o]);
        }
    }

    size_t cb = (size_t)ch * 3 * OI;
#pragma unroll
    for (int o = 0; o < OTB; ++o) {
        size_t s = (size_t)(og * OTB + o) * I + ii;
        spart[cb + s]          = aab[o];
        spart[cb + OI + s]     = asum[o];
        spart[cb + 2 * OI + s] = asq[o];
    }
}

__device__ __forceinline__ void statsfin_body(
    const float* __restrict__ spart, const float* __restrict__ grid,
    float* __restrict__ sc, float* __restrict__ st, int size, int s)
{
    float ab = 0.f, sm = 0.f, sq = 0.f;
#pragma unroll
    for (int k = 0; k < 4; ++k) {
        size_t base = (size_t)k * 3 * (size_t)size;
        ab += spart[base + s];
        sm += spart[base + (size_t)size + s];
        sq += spart[base + 2 * (size_t)size + s];
    }
    float range = grid[(size_t)s * 6 + 5] - grid[(size_t)s * 6 + 0] + 1e-4f;
    sc[s] = (ab * (1.0f / BATCH)) / range;
    float var = (sq - sm * sm * (1.0f / BATCH)) * (1.0f / (BATCH - 1));
    st[s] = sqrtf(fmaxf(var, 0.0f));
}

// ---------------------------------------------------------------------------
// K1: merge0(512) | basis0-dual(256 tiles, LDS transpose)     -> 768 blocks
// ---------------------------------------------------------------------------
__global__ __launch_bounds__(256) void k1_prep(
    const float* __restrict__ coef0, const float* __restrict__ ssp0,
    const float* __restrict__ sb0, float* __restrict__ wcA0,
    const float* __restrict__ x, const float* __restrict__ grid0,
    float4* __restrict__ basA0, float* __restrict__ siluT0,
    float* __restrict__ basB0, float* __restrict__ siluN0)
{
    __shared__ float lds[9][16][17];
    int bid = blockIdx.x, t = threadIdx.x;
    if (bid < 512)  { merge_body(coef0, ssp0, sb0, wcA0, bid * 256 + t); return; }
    int tile = bid - 512;                  // 16 bt x 16 it
    int bt = tile / 16, it = tile % 16;
    // phase 1: ii lane-fastest -> dense basB/siluN writes
    {
        int ii = it * 16 + (t & 15), b = bt * 16 + (t >> 4);
        float out[9];
        basis_eval(x[(size_t)b * 256 + ii], grid0, ii, out);
        float4* pB = (float4*)(basB0 + ((size_t)b * 256 + ii) * 8);
        pB[0] = make_float4(out[0], out[1], out[2], out[3]);
        pB[1] = make_float4(out[4], out[5], out[6], out[7]);
        siluN0[(size_t)b * 256 + ii] = out[8];
#pragma unroll
        for (int p = 0; p < 9; ++p) lds[p][t & 15][t >> 4] = out[p];
    }
    __syncthreads();
    // phase 2: b lane-fastest -> dense basA/siluT writes
    {
        int ii = it * 16 + (t >> 4), b = bt * 16 + (t & 15);
        float o[9];
#pragma unroll
        for (int p = 0; p < 9; ++p) o[p] = lds[p][t >> 4][t & 15];
        basA0[(size_t)(ii * 2 + 0) * BATCH + b] = make_float4(o[0], o[1], o[2], o[3]);
        basA0[(size_t)(ii * 2 + 1) * BATCH + b] = make_float4(o[4], o[5], o[6], o[7]);
        siluT0[(size_t)ii * BATCH + b] = o[8];
    }
}

// ---------------------------------------------------------------------------
// K2: xout0 (512: og32 x sp16) | stats0 (256: og64 x ch4) | merge1 (512)
//                                                          -> 1280 blocks
// ---------------------------------------------------------------------------
__global__ __launch_bounds__(256) void k2_sweep0(
    const float4* __restrict__ basA0, const float* __restrict__ siluT0,
    const float* __restrict__ wcA0, float* __restrict__ xpart0,
    const float* __restrict__ basB0, const float* __restrict__ siluN0,
    float* __restrict__ spart0,
    const float* __restrict__ coef1, const float* __restrict__ ssp1,
    const float* __restrict__ sb1, float* __restrict__ wcA1)
{
    int bid = blockIdx.x;
    if (bid < 512) {
        xout_body<256, 512>(basA0, siluT0, wcA0, xpart0, bid / 16, bid % 16);
    } else if (bid < 768) {
        int r = bid - 512;   // og in [0,64), ch in [0,4)
        stats_body<256, 512>(basB0, siluN0, wcA0, spart0, r / 4, r % 4, 0);
    } else {
        merge_body(coef1, ssp1, sb1, wcA1, (bid - 768) * 256 + threadIdx.x);
    }
}

// ---------------------------------------------------------------------------
// K3: basis1-dual (512 tiles, fused xmid, LDS transpose) | statsfin0 (512)
// ---------------------------------------------------------------------------
__global__ __launch_bounds__(256) void k3_basis1(
    const float* __restrict__ xpart0, const float* __restrict__ bias0,
    const float* __restrict__ grid1,
    float4* __restrict__ basA1, float* __restrict__ siluT1,
    float* __restrict__ basB1, float* __restrict__ siluN1,
    const float* __restrict__ spart0, const float* __restrict__ grid0,
    float* __restrict__ sc0, float* __restrict__ st0)
{
    __shared__ float lds[9][16][17];
    int bid = blockIdx.x, t = threadIdx.x;
    if (bid < 512) {
        int bt = bid / 32, it = bid % 32;       // b tiles 16, ii tiles 32 (I=512)
        // phase 1: b lane-fastest -> coalesced xpart reads, dense basA writes
        {
            int ii = it * 16 + (t >> 4), b = bt * 16 + (t & 15);
            float xv = bias0[ii];
#pragma unroll
            for (int k = 0; k < 16; ++k)
                xv += xpart0[(size_t)k * 131072 + (size_t)ii * 256 + b];
            float out[9];
            basis_eval(xv, grid1, ii, out);
            basA1[(size_t)(ii * 2 + 0) * BATCH + b] = make_float4(out[0], out[1], out[2], out[3]);
            basA1[(size_t)(ii * 2 + 1) * BATCH + b] = make_float4(out[4], out[5], out[6], out[7]);
            siluT1[(size_t)ii * BATCH + b] = out[8];
#pragma unroll
            for (int p = 0; p < 9; ++p) lds[p][t >> 4][t & 15] = out[p];
        }
        __syncthreads();
        // phase 2: ii lane-fastest -> dense basB/siluN writes
        {
            int ii = it * 16 + (t & 15), b = bt * 16 + (t >> 4);
            float o[9];
#pragma unroll
            for (int p = 0; p < 9; ++p) o[p] = lds[p][t & 15][t >> 4];
            float4* pB = (float4*)(basB1 + ((size_t)b * 512 + ii) * 8);
            pB[0] = make_float4(o[0], o[1], o[2], o[3]);
            pB[1] = make_float4(o[4], o[5], o[6], o[7]);
            siluN1[(size_t)b * 512 + ii] = o[8];
        }
        return;
    }
    statsfin_body(spart0, grid0, sc0, st0, 131072, (bid - 512) * 256 + t);
}

// ---------------------------------------------------------------------------
// K4: xout1 (512: og16 x sp32) | stats1 (256: og32 x ch4 x isp2) -> 768 blocks
// ---------------------------------------------------------------------------
__global__ __launch_bounds__(256) void k4_sweep1(
    const float4* __restrict__ basA1, const float* __restrict__ siluT1,
    const float* __restrict__ wcA1, float* __restrict__ xpart1,
    const float* __restrict__ basB1, const float* __restrict__ siluN1,
    float* __restrict__ spart1)
{
    int bid = blockIdx.x;
    if (bid < 512) {
        xout_body<512, 256>(basA1, siluT1, wcA1, xpart1, bid / 32, bid % 32);
    } else {
        int r = bid - 512;   // og in [0,32), rem: ch in [0,4), isp in {0,1}
        int og = r / 8, rem = r % 8;
        stats_body<512, 256>(basB1, siluN1, wcA1, spart1, og, rem % 4, rem / 4);
    }
}

// ---------------------------------------------------------------------------
// K5: xoutfin1 (256) | statsfin1 (512)                       -> 768 blocks
// ---------------------------------------------------------------------------
__global__ __launch_bounds__(256) void k5_fin(
    const float* __restrict__ xpart1, const float* __restrict__ bias1,
    float* __restrict__ x2,
    const float* __restrict__ spart1, const float* __restrict__ grid1,
    float* __restrict__ sc1, float* __restrict__ st1)
{
    int bid = blockIdx.x, t = threadIdx.x;
    if (bid < 256) {
        int oo = bid, b = t;
        float v = bias1[oo];
#pragma unroll
        for (int k = 0; k < 32; ++k)
            v += xpart1[(size_t)k * 65536 + (size_t)oo * 256 + b];
        x2[(size_t)b * 256 + oo] = v;
    } else {
        statsfin_body(spart1, grid1, sc1, st1, 131072, (bid - 256) * 256 + t);
    }
}

// ---------------------------------------------------------------------------
extern "C" void kernel_launch(void* const* d_in, const int* in_sizes, int n_in,
                              void* d_out, int out_size, void* d_ws, size_t ws_size,
                              hipStream_t stream)
{
    const float* x     = (const float*)d_in[0];
    const float* grid0 = (const float*)d_in[1];
    const float* coef0 = (const float*)d_in[2];
    const float* sb0   = (const float*)d_in[3];
    const float* ssp0  = (const float*)d_in[4];
    const float* bias0 = (const float*)d_in[5];
    const float* grid1 = (const float*)d_in[6];
    const float* coef1 = (const float*)d_in[7];
    const float* sb1   = (const float*)d_in[8];
    const float* ssp1  = (const float*)d_in[9];
    const float* bias1 = (const float*)d_in[10];

    float* out = (float*)d_out;
    float* x2  = out;                 // (256,256)
    float* sc0 = out + 65536;         // (512,256)
    float* st0 = out + 196608;        // (512,256)
    float* sc1 = out + 327680;        // (256,512)
    float* st1 = out + 458752;        // (256,512)

    // Workspace (~56 MB, all disjoint):
    float* w = (float*)d_ws;
    float* basA0  = w; w += 256 * 256 * 8;
    float* siluT0 = w; w += 256 * 256;
    float* basB0  = w; w += 256 * 256 * 8;
    float* siluN0 = w; w += 256 * 256;
    float* basA1  = w; w += 512 * 256 * 8;
    float* siluT1 = w; w += 512 * 256;
    float* basB1  = w; w += 512 * 256 * 8;
    float* siluN1 = w; w += 512 * 256;
    float* wcA0   = w; w += 12 * 512 * 256;
    float* wcA1   = w; w += 12 * 512 * 256;
    float* xpart0 = w; w += 16 * 512 * 256;     // [16][512][256]
    float* xpart1 = w; w += 32 * 256 * 256;     // [32][256][256]
    float* spart0 = w; w += 4 * 3 * 512 * 256;  // [4][3][131072]
    float* spart1 = w; w += 4 * 3 * 256 * 512;  // [4][3][131072]

    k1_prep<<<768, 256, 0, stream>>>(
        coef0, ssp0, sb0, wcA0,
        x, grid0, (float4*)basA0, siluT0, basB0, siluN0);

    k2_sweep0<<<1280, 256, 0, stream>>>(
        (const float4*)basA0, siluT0, wcA0, xpart0, basB0, siluN0, spart0,
        coef1, ssp1, sb1, wcA1);

    k3_basis1<<<1024, 256, 0, stream>>>(
        xpart0, bias0, grid1, (float4*)basA1, siluT1, basB1, siluN1,
        spart0, grid0, sc0, st0);

    k4_sweep1<<<768, 256, 0, stream>>>(
        (const float4*)basA1, siluT1, wcA1, xpart1, basB1, siluN1, spart1);

    k5_fin<<<768, 256, 0, stream>>>(
        xpart1, bias1, x2, spart1, grid1, sc1, st1);
}